// Round 6
// baseline (304.379 us; speedup 1.0000x reference)
//
#include <hip/hip_runtime.h>
#include <hip/hip_bf16.h>
#include <stdint.h>

#define DEV static __device__ __forceinline__

typedef __attribute__((ext_vector_type(8))) short bf16x8;
typedef __attribute__((ext_vector_type(4))) float f32x4;
typedef unsigned int u32;

static constexpr int T = 4096;
static constexpr int BATCH = 8;
static constexpr int DM = 1024;            // d_model = nhead*d_head
static constexpr int M1 = BATCH * T;       // 32768 rows into GEMM1
static constexpr int M2 = BATCH * (T + 1); // 32776 rows into GEMM2
static constexpr int M2P = 129 * 256;      // 33024 padded rows for S (256-tile)
static constexpr int NCH = 64;             // time chunks for scan
static constexpr int CL = T / NCH;         // 64 steps per chunk
static constexpr int NT = 16;              // K tiles (BK=64, K=1024)

DEV unsigned short f2bf(float f) {
  union { float f; unsigned u; } v; v.f = f;
  unsigned u = v.u;
  return (unsigned short)((u + 0x7fffu + ((u >> 16) & 1u)) >> 16);
}
DEV float bf2f(unsigned short s) {
  union { unsigned u; float f; } v; v.u = ((unsigned)s) << 16;
  return v.f;
}

DEV void gl_lds16(const unsigned short* g, unsigned short* lds) {
  __builtin_amdgcn_global_load_lds(
      (const __attribute__((address_space(1))) u32*)g,
      (__attribute__((address_space(3))) u32*)lds,
      16, 0, 0);
}

// scheduler-invisible LDS read (rule 18: caller must lgkmcnt(0)+sched_barrier(0))
DEV bf16x8 ds_read128(unsigned byte_off) {
  bf16x8 r;
  asm volatile("ds_read_b128 %0, %1" : "=v"(r) : "v"(byte_off));
  return r;
}

// ---------------- fp32 -> bf16 convert of inputs ----------------
__global__ void k_cvt_x(const float4* __restrict__ x, ushort4* __restrict__ o) {
  int i = blockIdx.x * 256 + threadIdx.x;
  float4 v = x[i];
  ushort4 r;
  r.x = f2bf(v.x); r.y = f2bf(v.y); r.z = f2bf(v.z); r.w = f2bf(v.w);
  o[i] = r;
}

// ------------- transpose + convert weights: Wt[n][k] = W[k][n] -------------
__global__ void k_transpose(const float* __restrict__ w0, const float* __restrict__ w1,
                            unsigned short* __restrict__ t0, unsigned short* __restrict__ t1) {
  __shared__ float tile[32][33];
  const float* src = blockIdx.z ? w1 : w0;
  unsigned short* dst = blockIdx.z ? t1 : t0;
  int bx = blockIdx.x * 32;
  int by = blockIdx.y * 32;
  int tx = threadIdx.x & 31, ty = threadIdx.x >> 5;
#pragma unroll
  for (int r = 0; r < 32; r += 8)
    tile[ty + r][tx] = src[(by + ty + r) * DM + bx + tx];
  __syncthreads();
#pragma unroll
  for (int r = 0; r < 32; r += 8)
    dst[(bx + ty + r) * DM + by + tx] = f2bf(tile[tx][ty + r]);
}

// ---------------- bf16 MFMA GEMM: C = A @ Wt^T + bias ----------------
// m201 8-phase derived-waits schedule, quadrant-consistent wave tiling:
// 256x256 tile, BK=64, 8 waves as 4M x 2N (per-wave 64rows x 128cols strip:
// m-frags split across both A-halves, n-frags across both B-halves).
// Phase (a,b): ALL waves read only A-half a + B-half b (4 A + 8 B ds_reads),
// compute 16 MFMA -> each half-region free after its 2 reader phases ->
// tile t+2's halves stream into slot t&1 while tile t computes.
// Waits: vmcnt(4) at phases 4 and 8 only (2 halves stay in flight, >=2-phase
// slack per load). 2 raw barriers/phase. LDS 2 slots x [A|B] x [half][128][64].
template <int MODE>
__global__ __launch_bounds__(512, 2) void k_gemm(const unsigned short* __restrict__ A16,
                                                 const unsigned short* __restrict__ Bt16,
                                                 const float* __restrict__ bias,
                                                 unsigned short* __restrict__ outb,
                                                 float* __restrict__ outf, int Mvalid) {
  __shared__ unsigned short lds[65536];  // 128 KiB: slot*32768 + B*16384 + half*8192 elems

  const int tid = threadIdx.x;
  const int w = tid >> 6, l = tid & 63;
  const int wmm = w & 3, wn = w >> 2;   // 4 m-slots x 2 n-slots
  const int rr = l & 15, kg = l >> 4;

  // bijective XCD swizzle (m204 general form)
  const int nwg = gridDim.x, orig = blockIdx.x;
  const int q8 = nwg >> 3, r8 = nwg & 7;
  const int xcd = orig & 7, idx = orig >> 3;
  const int wg = (xcd < r8 ? xcd * (q8 + 1) : r8 * (q8 + 1) + (xcd - r8) * q8) + idx;
  const int bm = wg >> 2, bn = wg & 3;
  const int blockM = bm * 256;
  const int blockN = bn * 256;

  f32x4 acc[4][8];  // [m-frag: a*2+mf'][n-frag: b*4+nf']
#pragma unroll
  for (int m = 0; m < 4; m++)
#pragma unroll
    for (int n = 0; n < 8; n++) acc[m][n] = (f32x4){0.f, 0.f, 0.f, 0.f};

  // ---- staging: half H of op in tile tt. Wave w covers rows (w*2+c)*8..+8
  // (c=0,1), lane->row +(l>>3), phys k-slot l&7 holds logical (l&7)^((l>>3)&7).
  const int sslot = (l & 7) ^ ((l >> 3) & 7);
  const unsigned short* pA[2];
  const unsigned short* pB[2];
#pragma unroll
  for (int c = 0; c < 2; c++) {
    int rp = (w * 2 + c) * 8 + (l >> 3);
    pA[c] = A16 + (size_t)(blockM + rp) * DM + sslot * 8;
    pB[c] = Bt16 + (size_t)(blockN + rp) * DM + sslot * 8;
  }

#define STAGE(tt, isB, H)                                                          \
  do {                                                                             \
    unsigned short* d_ = lds + ((tt) & 1) * 32768 + (isB) * 16384 + (H) * 8192 + w * 1024; \
    gl_lds16(pA[0] + ((isB) ? (pB[0] - pA[0]) : 0) + (size_t)(H) * 128 * DM + (size_t)(tt) * 64, d_);       \
    gl_lds16(pA[1] + ((isB) ? (pB[1] - pA[1]) : 0) + (size_t)(H) * 128 * DM + (size_t)(tt) * 64, d_ + 512); \
  } while (0)

  // ---- fragment read byte-offsets (within op+half region), swizzle g^(l&7)
  const unsigned ldsbase =
      (unsigned)(size_t)(__attribute__((address_space(3))) unsigned short*)lds;
  unsigned aoffv[2][2], boffv[4][2];
#pragma unroll
  for (int kh = 0; kh < 2; kh++) {
    int g = kh * 4 + kg;
#pragma unroll
    for (int mf = 0; mf < 2; mf++) {
      int r = wmm * 32 + mf * 16 + rr;
      aoffv[mf][kh] = ldsbase + r * 128 + (((g) ^ (l & 7)) * 16);
    }
#pragma unroll
    for (int nf = 0; nf < 4; nf++) {
      int r = wn * 64 + nf * 16 + rr;
      boffv[nf][kh] = ldsbase + r * 128 + (((g) ^ (l & 7)) * 16);
    }
  }

#define PH(SLOT, A_, B_, STG, VMW)                                                     \
  do {                                                                                 \
    bf16x8 aq_[2][2], bq_[4][2];                                                       \
    _Pragma("unroll") for (int kh = 0; kh < 2; kh++) {                                 \
      _Pragma("unroll") for (int nf = 0; nf < 4; nf++)                                 \
        bq_[nf][kh] = ds_read128(boffv[nf][kh] + ((SLOT) * 65536u + 32768u + (B_) * 16384u)); \
      _Pragma("unroll") for (int mf = 0; mf < 2; mf++)                                 \
        aq_[mf][kh] = ds_read128(aoffv[mf][kh] + ((SLOT) * 65536u + (A_) * 16384u));   \
    }                                                                                  \
    STG;                                                                               \
    VMW;                                                                               \
    __builtin_amdgcn_s_barrier();                                                      \
    asm volatile("s_waitcnt lgkmcnt(0)" ::: "memory");                                 \
    __builtin_amdgcn_sched_barrier(0);                                                 \
    __builtin_amdgcn_s_setprio(1);                                                     \
    _Pragma("unroll") for (int kh = 0; kh < 2; kh++)                                   \
      _Pragma("unroll") for (int mf = 0; mf < 2; mf++)                                 \
        _Pragma("unroll") for (int nf = 0; nf < 4; nf++)                               \
          acc[(A_) * 2 + mf][(B_) * 4 + nf] = __builtin_amdgcn_mfma_f32_16x16x32_bf16( \
              aq_[mf][kh], bq_[nf][kh], acc[(A_) * 2 + mf][(B_) * 4 + nf], 0, 0, 0);   \
    __builtin_amdgcn_s_setprio(0);                                                     \
    __builtin_amdgcn_s_barrier();                                                      \
  } while (0)

#define VM4 asm volatile("s_waitcnt vmcnt(4)" ::: "memory")
#define VM0 asm volatile("s_waitcnt vmcnt(0)" ::: "memory")

  // prologue: tile0 all 4 halves + tile1 A0,B0; wait leaves 2 halves in flight
  STAGE(0, 0, 0); STAGE(0, 1, 0); STAGE(0, 0, 1); STAGE(0, 1, 1);
  STAGE(1, 0, 0); STAGE(1, 1, 0);
  VM4;
  __builtin_amdgcn_s_barrier();

  for (int i = 0; i < NT / 2; ++i) {
    const int t0 = 2 * i;
    const bool g1 = (t0 + 2 < NT), g2 = (t0 + 3 < NT);
    // p1..p4: tile t0 (slot 0); stages per derived region-free order
    PH(0, 0, 0, STAGE(t0 + 1, 0, 1), );
    PH(0, 0, 1, STAGE(t0 + 1, 1, 1), );
    PH(0, 1, 0, if (g1) STAGE(t0 + 2, 0, 0), );
    PH(0, 1, 1, if (g1) STAGE(t0 + 2, 1, 0), if (g1) { VM4; } else { VM0; });
    // p5..p8: tile t0+1 (slot 1)
    PH(1, 0, 0, if (g1) STAGE(t0 + 2, 0, 1), );
    PH(1, 0, 1, if (g1) STAGE(t0 + 2, 1, 1), );
    PH(1, 1, 0, if (g2) STAGE(t0 + 3, 0, 0), );
    PH(1, 1, 1, if (g2) STAGE(t0 + 3, 1, 0), if (g2) { VM4; } else { VM0; });
  }
#undef PH
#undef STAGE

  // epilogue: C/D mapping col=lane&15, row=(lane>>4)*4+j  [m89-verified]
#pragma unroll
  for (int N = 0; N < 8; N++) {
    int col = blockN + (N >> 2) * 128 + wn * 64 + (N & 3) * 16 + (l & 15);
    float bv = bias[col];
#pragma unroll
    for (int M = 0; M < 4; M++) {
      int row = blockM + (M >> 1) * 128 + wmm * 32 + (M & 1) * 16 + (l >> 4) * 4;
#pragma unroll
      for (int j = 0; j < 4; j++) {
        float v = acc[M][N][j] + bv;
        if (MODE == 0) {
          outb[(size_t)(row + j) * DM + col] = f2bf(v);
        } else {
          if (row + j < Mvalid) outf[(size_t)(row + j) * DM + col] = v;
        }
      }
    }
  }
}

// ---------------- scan phase A ----------------
__global__ void k_scan_partial(const unsigned short* __restrict__ proj,
                               const float* __restrict__ logit,
                               const float* __restrict__ z0,
                               float* __restrict__ chunkend) {
  int b = blockIdx.x >> 6, c = blockIdx.x & 63;
  int ch = threadIdx.x;
  float a = 1.f / (1.f + expf(-logit[ch >> 6]));
  int t0 = c * CL;
  const unsigned short* p = proj + (size_t)(b * T + t0) * DM + ch;
  float pprev = (t0 == 0) ? z0[ch] : bf2f(p[-DM]);
  float s = 0.f;
  for (int j = 0; j < CL; j++) {
    float pv = bf2f(p[(size_t)j * DM]);
    s = a * s + (1.f - a) * (pv - pprev);
    pprev = pv;
  }
  chunkend[(b * NCH + c) * DM + ch] = s;
}

// ---------------- scan phase B ----------------
__global__ void k_scan_combine(const float* __restrict__ chunkend,
                               const float* __restrict__ logit,
                               const float* __restrict__ v0,
                               float* __restrict__ enter) {
  int b = blockIdx.x;
  int ch = threadIdx.x;
  float a = 1.f / (1.f + expf(-logit[ch >> 6]));
  float a2 = a * a, a4 = a2 * a2, a8 = a4 * a4, a16 = a8 * a8, a32 = a16 * a16;
  float aL = a32 * a32;
  float e = v0[ch];
  enter[(b * NCH + 0) * DM + ch] = e;
  for (int c = 1; c < NCH; c++) {
    e = aL * e + chunkend[(b * NCH + c - 1) * DM + ch];
    enter[(b * NCH + c) * DM + ch] = e;
  }
}

// ---------------- scan phase C ----------------
__global__ void k_scan_final(const unsigned short* __restrict__ proj,
                             const float* __restrict__ logit,
                             const float* __restrict__ z0,
                             const float* __restrict__ v0,
                             const float* __restrict__ enter,
                             unsigned short* __restrict__ S) {
  int b = blockIdx.x >> 6, c = blockIdx.x & 63;
  int ch = threadIdx.x;
  float a = 1.f / (1.f + expf(-logit[ch >> 6]));
  int t0 = c * CL;
  const unsigned short* p = proj + (size_t)(b * T + t0) * DM + ch;
  unsigned short* so = S + (size_t)(b * (T + 1) + t0 + 1) * DM + ch;
  float pprev = (t0 == 0) ? z0[ch] : bf2f(p[-DM]);
  float s = enter[(b * NCH + c) * DM + ch];
  if (c == 0) S[(size_t)b * (T + 1) * DM + ch] = f2bf(v0[ch]);
  for (int j = 0; j < CL; j++) {
    float pv = bf2f(p[(size_t)j * DM]);
    s = a * s + (1.f - a) * (pv - pprev);
    pprev = pv;
    so[(size_t)j * DM] = f2bf(s);
  }
}

__global__ void k_pad(unsigned short* __restrict__ S) {
  int i = blockIdx.x * 256 + threadIdx.x;
  if (i < (M2P - M2) * DM) S[(size_t)M2 * DM + i] = 0;
}

extern "C" void kernel_launch(void* const* d_in, const int* in_sizes, int n_in,
                              void* d_out, int out_size, void* d_ws, size_t ws_size,
                              hipStream_t stream) {
  const float* inputs = (const float*)d_in[0];
  const float* z0     = (const float*)d_in[1];
  const float* W_in   = (const float*)d_in[2];
  const float* b_in   = (const float*)d_in[3];
  const float* W_out  = (const float*)d_in[4];
  const float* b_out  = (const float*)d_in[5];
  const float* slogit = (const float*)d_in[6];
  const float* v0     = (const float*)d_in[7];
  float* out = (float*)d_out;

  char* ws = (char*)d_ws;
  unsigned short* X16   = (unsigned short*)(ws);
  unsigned short* P16   = (unsigned short*)(ws + 67108864);
  unsigned short* S16   = (unsigned short*)(ws + 134217728);
  unsigned short* WTin  = (unsigned short*)(ws + 201850880);
  unsigned short* WTout = (unsigned short*)(ws + 203948032);
  float* chunkend       = (float*)(ws + 206045184);
  float* enter          = (float*)(ws + 208142336);

  k_cvt_x<<<32768, 256, 0, stream>>>((const float4*)inputs, (ushort4*)X16);
  k_transpose<<<dim3(32, 32, 2), 256, 0, stream>>>(W_in, W_out, WTin, WTout);
  k_gemm<0><<<dim3((M1 / 256) * 4), 512, 0, stream>>>(X16, WTin, b_in, P16, nullptr, M1);
  k_scan_partial<<<dim3(BATCH * NCH), 1024, 0, stream>>>(P16, slogit, z0, chunkend);
  k_scan_combine<<<dim3(BATCH), 1024, 0, stream>>>(chunkend, slogit, v0, enter);
  k_scan_final<<<dim3(BATCH * NCH), 1024, 0, stream>>>(P16, slogit, z0, v0, enter, S16);
  k_pad<<<dim3(992), 256, 0, stream>>>(S16);
  k_gemm<1><<<dim3((M2P / 256) * 4), 512, 0, stream>>>(S16, WTout, b_out, nullptr, out, M2);
}